// Round 2
// baseline (3263.274 us; speedup 1.0000x reference)
//
#include <hip/hip_runtime.h>

#define N_NODES 10000
#define N_CFG   16
#define N_EDGES 40000
#define CHUNK   4          // configs processed per pipeline pass

// ---------------------------------------------------------------------------
// Phase 1: feature build
// ---------------------------------------------------------------------------

// T[j][v][d] = sum_t emb_layout[v][t] * lin_w[(140+4j+t)][d]   (18*8*256)
__global__ __launch_bounds__(256) void k_table(const float* __restrict__ emb_layout,
                                               const float* __restrict__ lin_w,
                                               float* __restrict__ T) {
    int b = blockIdx.x;          // 0..143
    int j = b >> 3, v = b & 7;
    int d = threadIdx.x;
    float s = 0.f;
#pragma unroll
    for (int t = 0; t < 4; ++t)
        s = fmaf(emb_layout[v * 4 + t], lin_w[(140 + 4 * j + t) * 256 + d], s);
    T[b * 256 + d] = s;
}

// base[n][d] = lin_b[d] + x_feat[n,:]@W[0:140] + emb_op[x_op[n]]@W[212:216]
__global__ __launch_bounds__(256) void k_base(const float* __restrict__ x_feat,
                                              const int* __restrict__ x_op,
                                              const float* __restrict__ emb_op,
                                              const float* __restrict__ lin_w,
                                              const float* __restrict__ lin_b,
                                              float* __restrict__ base) {
    __shared__ float xf[144];
    int n = blockIdx.x;
    int d = threadIdx.x;
    if (d < 140) xf[d] = x_feat[n * 140 + d];
    else if (d < 144) xf[d] = emb_op[x_op[n] * 4 + (d - 140)];
    __syncthreads();
    float s = lin_b[d];
#pragma unroll 4
    for (int k = 0; k < 140; ++k)
        s = fmaf(xf[k], lin_w[k * 256 + d], s);
#pragma unroll
    for (int t = 0; t < 4; ++t)
        s = fmaf(xf[140 + t], lin_w[(212 + t) * 256 + d], s);
    base[n * 256 + d] = s;
}

// A4[cy,n,d] = base[n,d] + sum_j T[j, cfg[cc*4+cy,n,j], d]
__global__ __launch_bounds__(256) void k_x0(const float* __restrict__ base,
                                            const float* __restrict__ T,
                                            const int* __restrict__ cfg,
                                            float* __restrict__ A,
                                            int cc) {
    __shared__ int idx[18];
    int n = blockIdx.x, cy = blockIdx.y;
    int cg = cc * CHUNK + cy;
    int d = threadIdx.x;
    if (d < 18) idx[d] = cfg[((size_t)cg * N_NODES + n) * 18 + d];
    __syncthreads();
    float s = base[n * 256 + d];
#pragma unroll
    for (int j = 0; j < 18; ++j)
        s += T[(j * 8 + idx[j]) * 256 + d];
    A[((size_t)cy * N_NODES + n) * 256 + d] = s;
}

// ---------------------------------------------------------------------------
// CSR build
// ---------------------------------------------------------------------------

__global__ void k_deg(const int* __restrict__ ei, int* __restrict__ deg) {
    int e = blockIdx.x * 256 + threadIdx.x;
    if (e < N_EDGES) atomicAdd(&deg[ei[N_EDGES + e]], 1);
}

__global__ __launch_bounds__(256) void k_scan(const int* __restrict__ deg,
                                              int* __restrict__ coff) {
    __shared__ int part[257];
    int t = threadIdx.x;
    const int CH = 40;  // 256*40 >= 10000
    int start = t * CH;
    int s = 0;
    for (int i = 0; i < CH; ++i) {
        int idx = start + i;
        if (idx < N_NODES) s += deg[idx];
    }
    part[t + 1] = s;
    if (t == 0) part[0] = 0;
    __syncthreads();
    if (t == 0)
        for (int i = 1; i <= 256; ++i) part[i] += part[i - 1];
    __syncthreads();
    int run = part[t];
    for (int i = 0; i < CH; ++i) {
        int idx = start + i;
        if (idx < N_NODES) { coff[idx] = run; run += deg[idx]; }
    }
    if (t == 0) coff[N_NODES] = part[256];
}

__global__ void k_invdeg(const int* __restrict__ deg, float* __restrict__ invd) {
    int n = blockIdx.x * 256 + threadIdx.x;
    if (n < N_NODES) invd[n] = 1.0f / fmaxf((float)deg[n], 1.0f);
}

__global__ void k_fill(const int* __restrict__ ei, const int* __restrict__ coff,
                       int* __restrict__ cur, int* __restrict__ csrc) {
    int e = blockIdx.x * 256 + threadIdx.x;
    if (e < N_EDGES) {
        int d = ei[N_EDGES + e];
        int s = ei[e];
        int pos = atomicAdd(&cur[d], 1);
        csrc[coff[d] + pos] = s;
    }
}

// fused weights: Wf[i][k][j]: k<256 -> wl[i][k][j], else wr[i][k-256][j]
__global__ void k_fuse_w(const float* __restrict__ wl, const float* __restrict__ wr,
                         float* __restrict__ Wf) {
    int idx = blockIdx.x * 256 + threadIdx.x;   // 0..524287
    int i = idx >> 17;
    int rem = idx & 131071;
    int r = rem >> 8, c = rem & 255;
    Wf[idx] = (r < 256) ? wl[i * 65536 + r * 256 + c]
                        : wr[i * 65536 + (r - 256) * 256 + c];
}

// ---------------------------------------------------------------------------
// Conv layer (per 4-config chunk)
// ---------------------------------------------------------------------------

// B[cy,n,:] = invd[n] * sum_{e in in(n)} A[cy, src_e, :]
__global__ __launch_bounds__(256) void k_agg(const float* __restrict__ A,
                                             float* __restrict__ B,
                                             const int* __restrict__ coff,
                                             const int* __restrict__ csrc,
                                             const float* __restrict__ invd) {
    int wave = threadIdx.x >> 6;
    int lane = threadIdx.x & 63;
    int n = blockIdx.x * 4 + wave;
    int cy = blockIdx.y;
    const float4* A4 = (const float4*)A;
    float4* B4 = (float4*)B;
    int e0 = coff[n], e1 = coff[n + 1];
    float4 acc = make_float4(0.f, 0.f, 0.f, 0.f);
    size_t cbase = (size_t)cy * N_NODES;
    for (int e = e0; e < e1; ++e) {
        int s = csrc[e];
        float4 v = A4[(cbase + s) * 64 + lane];
        acc.x += v.x; acc.y += v.y; acc.z += v.z; acc.w += v.w;
    }
    float iv = invd[n];
    acc.x *= iv; acc.y *= iv; acc.z *= iv; acc.w *= iv;
    B4[(cbase + n) * 64 + lane] = acc;
}

// A[r,j] = relu( B[r,:]@Wf[0:256] + A[r,:]@Wf[256:512] + bias[j] )
// BM=64, BN=256 (block owns its rows exclusively -> in-place on A is safe),
// BK=8, 256 threads, 8x8 per-thread tile.
__global__ __launch_bounds__(256) void k_gemm(const float* __restrict__ Bb,
                                              float* __restrict__ A,
                                              const float* __restrict__ Wf,
                                              const float* __restrict__ bias) {
    __shared__ float As[8][64];
    __shared__ float Ws[8][256];
    const int tid = threadIdx.x;
    const size_t r0 = (size_t)blockIdx.x * 64;
    const int lrow = tid >> 1, kq = tid & 1;       // A-tile staging (tid<128)
    const int wk = tid >> 5, wj = (tid & 31) * 4;  // W-tile staging (all)
    const int tm0 = (tid & 7) * 8;                 // thread row group
    const int tn0 = (tid >> 3) * 8;                // thread col group

    float acc[8][8];
#pragma unroll
    for (int i = 0; i < 8; ++i)
#pragma unroll
        for (int j = 0; j < 8; ++j) acc[i][j] = 0.f;

    for (int kt = 0; kt < 512; kt += 8) {
        const float* U = (kt < 256) ? Bb : A;
        const int cb = kt & 255;
        if (tid < 128) {
            float4 av = *(const float4*)(U + (r0 + lrow) * 256 + cb + kq * 4);
            As[kq * 4 + 0][lrow] = av.x;
            As[kq * 4 + 1][lrow] = av.y;
            As[kq * 4 + 2][lrow] = av.z;
            As[kq * 4 + 3][lrow] = av.w;
        }
        float4 w0 = *(const float4*)(Wf + (size_t)(kt + wk) * 256 + wj);
        float4 w1v = *(const float4*)(Wf + (size_t)(kt + wk) * 256 + wj + 128);
        *(float4*)&Ws[wk][wj] = w0;
        *(float4*)&Ws[wk][wj + 128] = w1v;
        __syncthreads();
#pragma unroll
        for (int kk = 0; kk < 8; ++kk) {
            float a[8], w[8];
            *(float4*)&a[0] = *(const float4*)&As[kk][tm0];
            *(float4*)&a[4] = *(const float4*)&As[kk][tm0 + 4];
            *(float4*)&w[0] = *(const float4*)&Ws[kk][tn0];
            *(float4*)&w[4] = *(const float4*)&Ws[kk][tn0 + 4];
#pragma unroll
            for (int i = 0; i < 8; ++i)
#pragma unroll
                for (int j = 0; j < 8; ++j)
                    acc[i][j] = fmaf(a[i], w[j], acc[i][j]);
        }
        __syncthreads();
    }

    float bv[8];
#pragma unroll
    for (int j = 0; j < 8; ++j) bv[j] = bias[tn0 + j];
#pragma unroll
    for (int i = 0; i < 8; ++i) {
        float* dst = A + (r0 + tm0 + i) * 256 + tn0;
#pragma unroll
        for (int jq = 0; jq < 2; ++jq) {
            float4 o;
            o.x = fmaxf(acc[i][jq * 4 + 0] + bv[jq * 4 + 0], 0.f);
            o.y = fmaxf(acc[i][jq * 4 + 1] + bv[jq * 4 + 1], 0.f);
            o.z = fmaxf(acc[i][jq * 4 + 2] + bv[jq * 4 + 2], 0.f);
            o.w = fmaxf(acc[i][jq * 4 + 3] + bv[jq * 4 + 3], 0.f);
            *(float4*)(dst + jq * 4) = o;
        }
    }
}

// ---------------------------------------------------------------------------
// Pool + head
// ---------------------------------------------------------------------------

__global__ __launch_bounds__(256) void k_pool(const float* __restrict__ A,
                                              float* __restrict__ g, int cc) {
    int cy = blockIdx.y;
    int d = threadIdx.x;
    size_t row0 = (size_t)cy * N_NODES + blockIdx.x * 250;
    float s = 0.f;
    for (int i = 0; i < 250; ++i)
        s += A[(row0 + i) * 256 + d];
    atomicAdd(&g[(cc * CHUNK + cy) * 256 + d], s);
}

__global__ __launch_bounds__(256) void k_head(const float* __restrict__ g,
                                              const float* __restrict__ w1,
                                              const float* __restrict__ b1,
                                              const float* __restrict__ w2,
                                              const float* __restrict__ b2,
                                              const float* __restrict__ w3,
                                              const float* __restrict__ b3,
                                              float* __restrict__ out) {
    __shared__ float ha[256];
    __shared__ float hb[256];
    __shared__ float red[4];
    int c = blockIdx.x;
    int d = threadIdx.x;
    ha[d] = g[c * 256 + d] / 10000.0f;
    __syncthreads();
    float s = b1[d];
#pragma unroll 4
    for (int k = 0; k < 256; ++k)
        s = fmaf(ha[k], w1[k * 256 + d], s);
    hb[d] = fmaxf(s, 0.f);
    __syncthreads();
    s = b2[d];
#pragma unroll 4
    for (int k = 0; k < 256; ++k)
        s = fmaf(hb[k], w2[k * 256 + d], s);
    ha[d] = fmaxf(s, 0.f);
    __syncthreads();
    float p = ha[d] * w3[d];
#pragma unroll
    for (int off = 32; off > 0; off >>= 1)
        p += __shfl_down(p, off, 64);
    if ((d & 63) == 0) red[d >> 6] = p;
    __syncthreads();
    if (d == 0)
        out[c] = red[0] + red[1] + red[2] + red[3] + b3[0];
}

// diagnostic: if workspace is too small, report its size via the output
__global__ void k_wsfail(float* __restrict__ out, float v) {
    out[threadIdx.x] = v;
}

// ---------------------------------------------------------------------------

extern "C" void kernel_launch(void* const* d_in, const int* in_sizes, int n_in,
                              void* d_out, int out_size, void* d_ws, size_t ws_size,
                              hipStream_t stream) {
    const int*   x_node_cfg = (const int*)  d_in[0];
    const float* x_feat     = (const float*)d_in[1];
    const int*   x_op       = (const int*)  d_in[2];
    const int*   edge_index = (const int*)  d_in[3];
    const float* emb_op     = (const float*)d_in[4];
    const float* emb_layout = (const float*)d_in[5];
    const float* lin_w      = (const float*)d_in[6];
    const float* lin_b      = (const float*)d_in[7];
    const float* conv_wl    = (const float*)d_in[8];
    const float* conv_bl    = (const float*)d_in[9];
    const float* conv_wr    = (const float*)d_in[10];
    const float* w1         = (const float*)d_in[11];
    const float* b1         = (const float*)d_in[12];
    const float* w2         = (const float*)d_in[13];
    const float* b2         = (const float*)d_in[14];
    const float* w3         = (const float*)d_in[15];
    const float* b3         = (const float*)d_in[16];
    float* out = (float*)d_out;

    // workspace layout (floats) — total 23,685,249 floats = 94.8 MB
    float* A    = (float*)d_ws;          // [CHUNK*N,256]  10,240,000
    float* Bb   = A + 10240000;          // [CHUNK*N,256]  10,240,000
    float* Wf   = Bb + 10240000;         // [4,512,256]       524,288
    float* T    = Wf + 524288;           // [18,8,256]         36,864
    float* base = T + 36864;             // [N,256]         2,560,000
    float* invd = base + 2560000;        // [N]
    float* g    = invd + 10000;          // [16,256] pad 4096
    int* deg    = (int*)(g + 4096);      // [N]
    int* coff   = deg + 10000;           // [N+1]
    int* cur    = coff + 10001;          // [N]
    int* csrc   = cur + 10000;           // [E]

    const size_t NEED = (size_t)23685249 * sizeof(float);
    if (ws_size < NEED) {
        // turn what would be a memory fault into a readable absmax signal
        k_wsfail<<<1, 16, 0, stream>>>(out, (float)ws_size * 1e-9f);
        return;
    }

    hipMemsetAsync(deg, 0, N_NODES * sizeof(int), stream);
    hipMemsetAsync(cur, 0, N_NODES * sizeof(int), stream);
    hipMemsetAsync(g, 0, 4096 * sizeof(float), stream);

    k_table<<<144, 256, 0, stream>>>(emb_layout, lin_w, T);
    k_base<<<N_NODES, 256, 0, stream>>>(x_feat, x_op, emb_op, lin_w, lin_b, base);
    k_deg<<<(N_EDGES + 255) / 256, 256, 0, stream>>>(edge_index, deg);
    k_scan<<<1, 256, 0, stream>>>(deg, coff);
    k_invdeg<<<(N_NODES + 255) / 256, 256, 0, stream>>>(deg, invd);
    k_fill<<<(N_EDGES + 255) / 256, 256, 0, stream>>>(edge_index, coff, cur, csrc);
    k_fuse_w<<<2048, 256, 0, stream>>>(conv_wl, conv_wr, Wf);

    for (int cc = 0; cc < N_CFG / CHUNK; ++cc) {
        k_x0<<<dim3(N_NODES, CHUNK), 256, 0, stream>>>(base, T, x_node_cfg, A, cc);
        for (int i = 0; i < 4; ++i) {
            k_agg<<<dim3(2500, CHUNK), 256, 0, stream>>>(A, Bb, coff, csrc, invd);
            k_gemm<<<625, 256, 0, stream>>>(Bb, A, Wf + i * 131072, conv_bl + i * 256);
        }
        k_pool<<<dim3(40, CHUNK), 256, 0, stream>>>(A, g, cc);
    }

    k_head<<<16, 256, 0, stream>>>(g, w1, b1, w2, b2, w3, b3, out);
}

// Round 3
// 1619.714 us; speedup vs baseline: 2.0147x; 2.0147x over previous
//
#include <hip/hip_runtime.h>

#define N_NODES 10000
#define N_CFG   16
#define N_EDGES 40000
#define CHUNK   4                 // configs per pipeline pass
#define ROWS    (CHUNK * N_NODES) // 40000
#define ROWS_PAD 40064            // 313 * 128
#define UW      768               // U row: [agg 256 | x_ping 256 | x_pong 256]

typedef __attribute__((ext_vector_type(8))) short bf16x8;
typedef __attribute__((ext_vector_type(4))) float floatx4;

__device__ __forceinline__ unsigned short f2bf(float f) {
    union { float f; unsigned int u; } v; v.f = f;
    unsigned int r = (v.u + 0x7fffu + ((v.u >> 16) & 1u)) >> 16;  // RNE
    return (unsigned short)r;
}
__device__ __forceinline__ float bf2f(unsigned short h) {
    union { unsigned int u; float f; } v; v.u = ((unsigned int)h) << 16;
    return v.f;
}

// ---------------------------------------------------------------------------
// Feature build
// ---------------------------------------------------------------------------

// T[j][v][d] = sum_t emb_layout[v][t] * lin_w[(140+4j+t)][d]
__global__ __launch_bounds__(256) void k_table(const float* __restrict__ emb_layout,
                                               const float* __restrict__ lin_w,
                                               float* __restrict__ T) {
    int b = blockIdx.x;  // 0..143
    int j = b >> 3, v = b & 7;
    int d = threadIdx.x;
    float s = 0.f;
#pragma unroll
    for (int t = 0; t < 4; ++t)
        s = fmaf(emb_layout[v * 4 + t], lin_w[(140 + 4 * j + t) * 256 + d], s);
    T[b * 256 + d] = s;
}

__global__ __launch_bounds__(256) void k_base(const float* __restrict__ x_feat,
                                              const int* __restrict__ x_op,
                                              const float* __restrict__ emb_op,
                                              const float* __restrict__ lin_w,
                                              const float* __restrict__ lin_b,
                                              float* __restrict__ base) {
    __shared__ float xf[144];
    int n = blockIdx.x;
    int d = threadIdx.x;
    if (d < 140) xf[d] = x_feat[n * 140 + d];
    else if (d < 144) xf[d] = emb_op[x_op[n] * 4 + (d - 140)];
    __syncthreads();
    float s = lin_b[d];
#pragma unroll 4
    for (int k = 0; k < 140; ++k)
        s = fmaf(xf[k], lin_w[k * 256 + d], s);
#pragma unroll
    for (int t = 0; t < 4; ++t)
        s = fmaf(xf[140 + t], lin_w[(212 + t) * 256 + d], s);
    base[n * 256 + d] = s;
}

// x0 -> U x_ping (cols 256..511), bf16
__global__ __launch_bounds__(256) void k_x0(const float* __restrict__ base,
                                            const float* __restrict__ T,
                                            const int* __restrict__ cfg,
                                            unsigned short* __restrict__ U,
                                            int cc) {
    __shared__ int idx[18];
    int n = blockIdx.x, cy = blockIdx.y;
    int cg = cc * CHUNK + cy;
    int d = threadIdx.x;
    if (d < 18) idx[d] = cfg[((size_t)cg * N_NODES + n) * 18 + d];
    __syncthreads();
    float s = base[n * 256 + d];
#pragma unroll
    for (int j = 0; j < 18; ++j)
        s += T[(j * 8 + idx[j]) * 256 + d];
    U[(size_t)(cy * N_NODES + n) * UW + 256 + d] = f2bf(s);
}

// ---------------------------------------------------------------------------
// CSR build
// ---------------------------------------------------------------------------

__global__ void k_deg(const int* __restrict__ ei, int* __restrict__ deg) {
    int e = blockIdx.x * 256 + threadIdx.x;
    if (e < N_EDGES) atomicAdd(&deg[ei[N_EDGES + e]], 1);
}

__global__ __launch_bounds__(256) void k_scan(const int* __restrict__ deg,
                                              int* __restrict__ coff) {
    __shared__ int part[257];
    int t = threadIdx.x;
    const int CH = 40;
    int start = t * CH;
    int s = 0;
    for (int i = 0; i < CH; ++i) {
        int idx = start + i;
        if (idx < N_NODES) s += deg[idx];
    }
    part[t + 1] = s;
    if (t == 0) part[0] = 0;
    __syncthreads();
    if (t == 0)
        for (int i = 1; i <= 256; ++i) part[i] += part[i - 1];
    __syncthreads();
    int run = part[t];
    for (int i = 0; i < CH; ++i) {
        int idx = start + i;
        if (idx < N_NODES) { coff[idx] = run; run += deg[idx]; }
    }
    if (t == 0) coff[N_NODES] = part[256];
}

__global__ void k_invdeg(const int* __restrict__ deg, float* __restrict__ invd) {
    int n = blockIdx.x * 256 + threadIdx.x;
    if (n < N_NODES) invd[n] = 1.0f / fmaxf((float)deg[n], 1.0f);
}

__global__ void k_fill(const int* __restrict__ ei, const int* __restrict__ coff,
                       int* __restrict__ cur, int* __restrict__ csrc) {
    int e = blockIdx.x * 256 + threadIdx.x;
    if (e < N_EDGES) {
        int d = ei[N_EDGES + e];
        int s = ei[e];
        int pos = atomicAdd(&cur[d], 1);
        csrc[coff[d] + pos] = s;
    }
}

// WT[i][n][k]: k in [0,512) = bf16_hi(Wfused[k][n]); k in [512,1024) = bf16_lo
// Wfused[k][n] = k<256 ? wl[i][k][n] : wr[i][k-256][n]
__global__ void k_wsplit(const float* __restrict__ wl, const float* __restrict__ wr,
                         unsigned short* __restrict__ WT) {
    int t = blockIdx.x * 256 + threadIdx.x;  // < 524288
    int i = t >> 17;
    int r = (t >> 8) & 511;
    int nn = t & 255;
    float w = (r < 256) ? wl[i * 65536 + r * 256 + nn]
                        : wr[i * 65536 + (r - 256) * 256 + nn];
    unsigned short hi = f2bf(w);
    unsigned short lo = f2bf(w - bf2f(hi));
    size_t b = (size_t)i * 262144 + (size_t)nn * 1024;
    WT[b + r] = hi;
    WT[b + 512 + r] = lo;
}

// ---------------------------------------------------------------------------
// Aggregation: U agg cols (0..255) <- mean of U x cols (xoff..) over in-edges
// ---------------------------------------------------------------------------

__global__ __launch_bounds__(256) void k_agg(unsigned short* __restrict__ U,
                                             const int* __restrict__ coff,
                                             const int* __restrict__ csrc,
                                             const float* __restrict__ invd,
                                             int xoff) {
    int wave = threadIdx.x >> 6, lane = threadIdx.x & 63;
    int n = blockIdx.x * 4 + wave;
    int cy = blockIdx.y;
    int e0 = coff[n], e1 = coff[n + 1];
    size_t cbase = (size_t)cy * N_NODES;
    float a0 = 0.f, a1 = 0.f, a2 = 0.f, a3 = 0.f;
    for (int e = e0; e < e1; ++e) {
        int s = csrc[e];
        uint2 v = *(const uint2*)(U + (cbase + s) * UW + xoff + lane * 4);
        a0 += bf2f(v.x & 0xffff); a1 += bf2f(v.x >> 16);
        a2 += bf2f(v.y & 0xffff); a3 += bf2f(v.y >> 16);
    }
    float iv = invd[n];
    uint2 o;
    o.x = (unsigned int)f2bf(a0 * iv) | ((unsigned int)f2bf(a1 * iv) << 16);
    o.y = (unsigned int)f2bf(a2 * iv) | ((unsigned int)f2bf(a3 * iv) << 16);
    *(uint2*)(U + (cbase + n) * UW + lane * 4) = o;
}

// ---------------------------------------------------------------------------
// MFMA GEMM: x_out = relu( [agg|x_in] @ (W_hi + W_lo) + bias ), virtual K=1024
// BM=128, BN=128, BK=32; 4 waves, each 64x64 via 4x4 16x16x32 bf16 MFMA.
// In-place safe: reads x_in cols, writes x_out cols (disjoint ping-pong).
// ---------------------------------------------------------------------------

__global__ __launch_bounds__(256) void k_gemm(unsigned short* __restrict__ U,
                                              const unsigned short* __restrict__ WTl,
                                              const float* __restrict__ bias,
                                              int xin, int xout) {
    __shared__ unsigned short Asm[4096];  // [128 rows][32 k] (xor-swizzled 16B slots)
    __shared__ unsigned short Bsm[4096];  // [128 n   ][32 k]
    const int tid = threadIdx.x;
    const int lane = tid & 63;
    const int wave = tid >> 6;
    const int wm = wave >> 1, wn = wave & 1;
    const size_t r0 = (size_t)blockIdx.x * 128;
    const int n0 = blockIdx.y * 128;

    // staging coords: slot l = it*256 + tid; row = l>>2, s = l&3, gc = s ^ ((row>>1)&3)
    const int row0s = tid >> 2;
    const int gc0 = (tid & 3) ^ ((row0s >> 1) & 3);
    const int row1s = 64 + (tid >> 2);
    const int gc1 = (tid & 3) ^ ((row1s >> 1) & 3);

    floatx4 acc[4][4];
#pragma unroll
    for (int i = 0; i < 4; ++i)
#pragma unroll
        for (int j = 0; j < 4; ++j) acc[i][j] = (floatx4){0.f, 0.f, 0.f, 0.f};

    const int colg = lane & 15, kg = lane >> 4;
    int aoff[4], boff[4];
#pragma unroll
    for (int t = 0; t < 4; ++t) {
        int ar = wm * 64 + t * 16 + colg;
        aoff[t] = ar * 32 + ((kg ^ ((ar >> 1) & 3)) << 3);
        int br = wn * 64 + t * 16 + colg;
        boff[t] = br * 32 + ((kg ^ ((br >> 1) & 3)) << 3);
    }

    uint4 ra0, ra1, rb0, rb1;
    {   // prologue: tile kt=0 (c=0 -> agg cols)
        ra0 = *(const uint4*)(U + (r0 + row0s) * UW + 0 + gc0 * 8);
        ra1 = *(const uint4*)(U + (r0 + row1s) * UW + 0 + gc1 * 8);
        rb0 = *(const uint4*)(WTl + (size_t)(n0 + row0s) * 1024 + 0 + gc0 * 8);
        rb1 = *(const uint4*)(WTl + (size_t)(n0 + row1s) * 1024 + 0 + gc1 * 8);
    }

    for (int kt = 0; kt < 1024; kt += 32) {
        __syncthreads();
        *(uint4*)(Asm + (size_t)tid * 8) = ra0;
        *(uint4*)(Asm + 2048 + (size_t)tid * 8) = ra1;
        *(uint4*)(Bsm + (size_t)tid * 8) = rb0;
        *(uint4*)(Bsm + 2048 + (size_t)tid * 8) = rb1;
        __syncthreads();

        if (kt + 32 < 1024) {  // prefetch next tile (overlaps MFMA below)
            int kn = kt + 32;
            int c = kn & 511;
            int ucol = (c < 256) ? c : (xin + c - 256);
            ra0 = *(const uint4*)(U + (r0 + row0s) * UW + ucol + gc0 * 8);
            ra1 = *(const uint4*)(U + (r0 + row1s) * UW + ucol + gc1 * 8);
            rb0 = *(const uint4*)(WTl + (size_t)(n0 + row0s) * 1024 + kn + gc0 * 8);
            rb1 = *(const uint4*)(WTl + (size_t)(n0 + row1s) * 1024 + kn + gc1 * 8);
        }

        bf16x8 a[4], b[4];
#pragma unroll
        for (int t = 0; t < 4; ++t) a[t] = *(const bf16x8*)(Asm + aoff[t]);
#pragma unroll
        for (int t = 0; t < 4; ++t) b[t] = *(const bf16x8*)(Bsm + boff[t]);
#pragma unroll
        for (int ti = 0; ti < 4; ++ti)
#pragma unroll
            for (int tj = 0; tj < 4; ++tj)
                acc[ti][tj] = __builtin_amdgcn_mfma_f32_16x16x32_bf16(
                    a[ti], b[tj], acc[ti][tj], 0, 0, 0);
    }

    const int quad = lane >> 4;
#pragma unroll
    for (int tj = 0; tj < 4; ++tj) {
        int nn = n0 + wn * 64 + tj * 16 + colg;
        float bv = bias[nn];
#pragma unroll
        for (int ti = 0; ti < 4; ++ti) {
#pragma unroll
            for (int r = 0; r < 4; ++r) {
                size_t mm = r0 + (size_t)(wm * 64 + ti * 16 + quad * 4 + r);
                float y = acc[ti][tj][r] + bv;
                U[mm * UW + xout + nn] = f2bf(fmaxf(y, 0.f));
            }
        }
    }
}

// ---------------------------------------------------------------------------
// Pool + head
// ---------------------------------------------------------------------------

__global__ __launch_bounds__(256) void k_pool(const unsigned short* __restrict__ U,
                                              float* __restrict__ g, int cc) {
    int cy = blockIdx.y;
    int d = threadIdx.x;
    size_t row0 = (size_t)cy * N_NODES + blockIdx.x * 250;
    float s = 0.f;
    for (int i = 0; i < 250; ++i)
        s += bf2f(U[(row0 + i) * UW + 256 + d]);
    atomicAdd(&g[(cc * CHUNK + cy) * 256 + d], s);
}

__global__ __launch_bounds__(256) void k_head(const float* __restrict__ g,
                                              const float* __restrict__ w1,
                                              const float* __restrict__ b1,
                                              const float* __restrict__ w2,
                                              const float* __restrict__ b2,
                                              const float* __restrict__ w3,
                                              const float* __restrict__ b3,
                                              float* __restrict__ out) {
    __shared__ float ha[256];
    __shared__ float hb[256];
    __shared__ float red[4];
    int c = blockIdx.x;
    int d = threadIdx.x;
    ha[d] = g[c * 256 + d] / 10000.0f;
    __syncthreads();
    float s = b1[d];
#pragma unroll 4
    for (int k = 0; k < 256; ++k)
        s = fmaf(ha[k], w1[k * 256 + d], s);
    hb[d] = fmaxf(s, 0.f);
    __syncthreads();
    s = b2[d];
#pragma unroll 4
    for (int k = 0; k < 256; ++k)
        s = fmaf(hb[k], w2[k * 256 + d], s);
    ha[d] = fmaxf(s, 0.f);
    __syncthreads();
    float p = ha[d] * w3[d];
#pragma unroll
    for (int off = 32; off > 0; off >>= 1)
        p += __shfl_down(p, off, 64);
    if ((d & 63) == 0) red[d >> 6] = p;
    __syncthreads();
    if (d == 0)
        out[c] = red[0] + red[1] + red[2] + red[3] + b3[0];
}

__global__ void k_wsfail(float* __restrict__ out, float v) {
    out[threadIdx.x] = v;
}

// ---------------------------------------------------------------------------

extern "C" void kernel_launch(void* const* d_in, const int* in_sizes, int n_in,
                              void* d_out, int out_size, void* d_ws, size_t ws_size,
                              hipStream_t stream) {
    const int*   x_node_cfg = (const int*)  d_in[0];
    const float* x_feat     = (const float*)d_in[1];
    const int*   x_op       = (const int*)  d_in[2];
    const int*   edge_index = (const int*)  d_in[3];
    const float* emb_op     = (const float*)d_in[4];
    const float* emb_layout = (const float*)d_in[5];
    const float* lin_w      = (const float*)d_in[6];
    const float* lin_b      = (const float*)d_in[7];
    const float* conv_wl    = (const float*)d_in[8];
    const float* conv_bl    = (const float*)d_in[9];
    const float* conv_wr    = (const float*)d_in[10];
    const float* w1         = (const float*)d_in[11];
    const float* b1         = (const float*)d_in[12];
    const float* w2         = (const float*)d_in[13];
    const float* b2         = (const float*)d_in[14];
    const float* w3         = (const float*)d_in[15];
    const float* b3         = (const float*)d_in[16];
    float* out = (float*)d_out;

    // workspace layout — total 74,359,300 bytes (~74.4 MB)
    unsigned short* U  = (unsigned short*)d_ws;        // [40064][768] bf16
    float* base = (float*)(U + (size_t)ROWS_PAD * UW); // [10000][256] f32
    float* T    = base + 2560000;                      // [18][8][256]
    float* invd = T + 36864;                           // [10000]
    float* g    = invd + 10000;                        // [16][256] pad 4096
    unsigned short* WT = (unsigned short*)(g + 4096);  // [4][256][1024] bf16
    int* deg  = (int*)(WT + 1048576);                  // [10000]
    int* coff = deg + 10000;                           // [10001]
    int* cur  = coff + 10001;                          // [10000]
    int* csrc = cur + 10000;                           // [40000]

    const size_t NEED = 74359300;
    if (ws_size < NEED) {
        k_wsfail<<<1, 16, 0, stream>>>(out, (float)ws_size * 1e-9f);
        return;
    }

    hipMemsetAsync(deg, 0, N_NODES * sizeof(int), stream);
    hipMemsetAsync(cur, 0, N_NODES * sizeof(int), stream);
    hipMemsetAsync(g, 0, 4096 * sizeof(float), stream);

    k_table<<<144, 256, 0, stream>>>(emb_layout, lin_w, T);
    k_base<<<N_NODES, 256, 0, stream>>>(x_feat, x_op, emb_op, lin_w, lin_b, base);
    k_deg<<<(N_EDGES + 255) / 256, 256, 0, stream>>>(edge_index, deg);
    k_scan<<<1, 256, 0, stream>>>(deg, coff);
    k_invdeg<<<(N_NODES + 255) / 256, 256, 0, stream>>>(deg, invd);
    k_fill<<<(N_EDGES + 255) / 256, 256, 0, stream>>>(edge_index, coff, cur, csrc);
    k_wsplit<<<2048, 256, 0, stream>>>(conv_wl, conv_wr, WT);

    for (int cc = 0; cc < N_CFG / CHUNK; ++cc) {
        k_x0<<<dim3(N_NODES, CHUNK), 256, 0, stream>>>(base, T, x_node_cfg, U, cc);
        for (int i = 0; i < 4; ++i) {
            int xin = (i & 1) ? 512 : 256;
            int xout = (i & 1) ? 256 : 512;
            k_agg<<<dim3(2500, CHUNK), 256, 0, stream>>>(U, coff, csrc, invd, xin);
            k_gemm<<<dim3(313, 2), 256, 0, stream>>>(U, WT + i * 262144,
                                                     conv_bl + i * 256, xin, xout);
        }
        // after layers 0..3 the final x sits at offset 256
        k_pool<<<dim3(40, CHUNK), 256, 0, stream>>>(U, g, cc);
    }

    k_head<<<16, 256, 0, stream>>>(g, w1, b1, w2, b2, w3, b3, out);
}